// Round 8
// baseline (541.340 us; speedup 1.0000x reference)
//
#include <hip/hip_runtime.h>
#include <hip/hip_bf16.h>

#define N 8192
#define IND 128
#define OUTD 128
#define JC 8
#define JLEN 1024   /* N/JC */
#define TSTEPS 32   /* JLEN/32 kc-steps per block */
#define NW64 (N / 64)

typedef float f32x4 __attribute__((ext_vector_type(4)));
typedef short s16x8 __attribute__((ext_vector_type(8)));

static __device__ inline unsigned short f2bf(float f) {
    union { float f; unsigned u; } v; v.f = f;
    unsigned u = v.u + 0x7fffu + ((v.u >> 16) & 1u);
    return (unsigned short)(u >> 16);
}
static __device__ inline float bf2f(unsigned short b) {
    union { unsigned u; float f; } v; v.u = ((unsigned)b) << 16;
    return v.f;
}
static __device__ __forceinline__ unsigned pkbf(float a, float b) {
    __hip_bfloat162 t = __float22bfloat162_rn(make_float2(a, b));
    unsigned u;
    __builtin_memcpy(&u, &t, 4);
    return u;
}

// ---------------------------------------------------------------------------
// Kernel 0: compress binary adj (268 MB) -> bitmask (8.4 MB). Streaming read.
// ---------------------------------------------------------------------------
__global__ __launch_bounds__(256) void k0_pack(const float* __restrict__ adj,
                                               unsigned long long* __restrict__ bits) {
    const int row = blockIdx.x;
    const int wave = threadIdx.x >> 6, lane = threadIdx.x & 63;
    const float* src = adj + (size_t)row * N + wave * 2048;
    unsigned long long acc = 0;
#pragma unroll
    for (int t = 0; t < 32; ++t) {
        float v = src[t * 64 + lane];
        unsigned long long b = __ballot(v != 0.0f);
        if (lane == t) acc = b;   // park word t in lane t
    }
    if (lane < 32)
        bits[(size_t)row * NW64 + wave * 32 + lane] = acc;
}

// ---------------------------------------------------------------------------
// Kernel 1: h = x @ W  (bf16 MFMA), store transposed bf16 hT[c][i] (128 x N).
// ---------------------------------------------------------------------------
__global__ __launch_bounds__(256) void k1_xw(const float* __restrict__ x,
                                             const float* __restrict__ W,
                                             unsigned short* __restrict__ hT) {
    __shared__ unsigned short Wl[128 * 130];
    const int tid = threadIdx.x;
    {
        int k = tid >> 1, n0 = (tid & 1) * 64;
        const float4* src = (const float4*)(W + k * 128 + n0);
#pragma unroll
        for (int v = 0; v < 16; ++v) {
            float4 f = src[v];
            int base = k * 130 + n0 + v * 4;
            Wl[base + 0] = f2bf(f.x);
            Wl[base + 1] = f2bf(f.y);
            Wl[base + 2] = f2bf(f.z);
            Wl[base + 3] = f2bf(f.w);
        }
    }
    __syncthreads();
    const int wave = tid >> 6, lane = tid & 63;
    const int m = lane & 15, quad = lane >> 4;
    const int ibase = blockIdx.x * 64 + wave * 16;
    const int irow = ibase + m;

    f32x4 acc[8];
#pragma unroll
    for (int t = 0; t < 8; ++t) acc[t] = (f32x4){0.f, 0.f, 0.f, 0.f};

#pragma unroll
    for (int ks = 0; ks < 4; ++ks) {
        const int k0 = ks * 32 + quad * 8;
        const float4* xp = (const float4*)(x + (size_t)irow * 128 + k0);
        float4 xa = xp[0], xb = xp[1];
        s16x8 afrag;
        afrag[0] = (short)f2bf(xa.x); afrag[1] = (short)f2bf(xa.y);
        afrag[2] = (short)f2bf(xa.z); afrag[3] = (short)f2bf(xa.w);
        afrag[4] = (short)f2bf(xb.x); afrag[5] = (short)f2bf(xb.y);
        afrag[6] = (short)f2bf(xb.z); afrag[7] = (short)f2bf(xb.w);
#pragma unroll
        for (int nt = 0; nt < 8; ++nt) {
            const int n = nt * 16 + m;
            s16x8 bfrag;
#pragma unroll
            for (int j = 0; j < 8; ++j)
                bfrag[j] = (short)Wl[(k0 + j) * 130 + n];
            acc[nt] = __builtin_amdgcn_mfma_f32_16x16x32_bf16(afrag, bfrag, acc[nt], 0, 0, 0);
        }
    }
#pragma unroll
    for (int nt = 0; nt < 8; ++nt) {
        const int c = nt * 16 + m;
        const int i0 = ibase + quad * 4;
        ushort4 pk;
        pk.x = f2bf(acc[nt][0]); pk.y = f2bf(acc[nt][1]);
        pk.z = f2bf(acc[nt][2]); pk.w = f2bf(acc[nt][3]);
        *(ushort4*)(hT + (size_t)c * N + i0) = pk;
    }
}

// ---------------------------------------------------------------------------
// Kernel 2: per-node separable arrays.
// w_ij = exp(leaky(es_i + ed_j)) = max(A_i*B_j, C_i*D_j);  BD[j]={B0,D0,B1,D1}
// ---------------------------------------------------------------------------
__global__ __launch_bounds__(256) void k2_e(const unsigned short* __restrict__ hT,
                                            const float* __restrict__ a_src,
                                            const float* __restrict__ a_dst,
                                            float* __restrict__ As, float* __restrict__ Cs,
                                            float4* __restrict__ BD) {
    const int i = blockIdx.x * 256 + threadIdx.x;
    float es0 = 0.f, ed0 = 0.f, es1 = 0.f, ed1 = 0.f;
#pragma unroll 8
    for (int c = 0; c < 128; ++c) {
        float v = bf2f(hT[(size_t)c * N + i]);
        float as = a_src[c], ad = a_dst[c];
        if (c < 64) { es0 += v * as; ed0 += v * ad; }
        else        { es1 += v * as; ed1 += v * ad; }
    }
    As[i]     = __expf(es0);
    As[N + i] = __expf(es1);
    Cs[i]     = __expf(0.2f * es0);
    Cs[N + i] = __expf(0.2f * es1);
    float4 bd;
    bd.x = __expf(ed0); bd.y = __expf(0.2f * ed0);
    bd.z = __expf(ed1); bd.w = __expf(0.2f * ed1);
    BD[i] = bd;
}

// ---------------------------------------------------------------------------
// Kernel 3 (main): bitmask adj (L2), hT REGISTER-PIPELINED one kc-step ahead
// (8 fragments double-buffered; L2 latency covered by a full step), BD from
// LDS. Epilogue: acc -> LDS (129-pitch) -> coalesced rows -> fp32 atomicAdd
// into Up/Lp (reduces over j-chunks in place; no fp16 partial round-trip).
// grid = (128 i-tiles, 8 j-chunks); block = 256 thr = 4 waves, 16 rows/wave.
// ---------------------------------------------------------------------------
__global__ __launch_bounds__(256, 3) void k3_main(const unsigned long long* __restrict__ bits,
                                                  const unsigned short* __restrict__ hT,
                                                  const float* __restrict__ As,
                                                  const float* __restrict__ Cs,
                                                  const float4* __restrict__ BD,
                                                  float* __restrict__ Up,
                                                  float* __restrict__ Lp) {
    __shared__ float smem[4 * 16 * 129];      // 33 KB; aliased: BDl during loop
    float4* BDl = (float4*)smem;              // needs 18.5 KB <= 33 KB
    const int tid = threadIdx.x;
    const int wave = tid >> 6, lane = tid & 63;
    const int m = lane & 15, quad = lane >> 4;
    const int ibase = blockIdx.x * 64 + wave * 16;
    const int irow = ibase + m;
    const int jc = blockIdx.y;
    const int j0 = jc * JLEN;

    for (int t = tid; t < JLEN; t += 256) BDl[t + (t >> 3)] = BD[j0 + t];

    const float A0 = As[irow], C0 = Cs[irow];
    const float A1 = As[N + irow], C1 = Cs[N + irow];

    f32x4 acc[2][4];
#pragma unroll
    for (int h = 0; h < 2; ++h)
#pragma unroll
        for (int nt = 0; nt < 4; ++nt) acc[h][nt] = (f32x4){0.f, 0.f, 0.f, 0.f};
    f32x4 accS[2];
    accS[0] = (f32x4){0.f, 0.f, 0.f, 0.f};
    accS[1] = (f32x4){0.f, 0.f, 0.f, 0.f};

    s16x8 ones;
#pragma unroll
    for (int t = 0; t < 8; ++t) ones[t] = (short)0x3F80;

    const unsigned long long* mrow = bits + (size_t)irow * NW64 + (j0 >> 6);
    __syncthreads();

    // hT fragment double-buffer: [buf][head*4 + nt]
    s16x8 hb[2][8];
    {
        const int jq0 = j0 + quad * 8;
#pragma unroll
        for (int nt = 0; nt < 4; ++nt) {
            hb[0][nt]     = *(const s16x8*)(hT + (size_t)(nt * 16 + m) * N + jq0);
            hb[0][4 + nt] = *(const s16x8*)(hT + (size_t)(nt * 16 + m + 64) * N + jq0);
        }
    }

#pragma unroll 4
    for (int t = 0; t < TSTEPS; ++t) {
        const int cur = t & 1, nxt = cur ^ 1;
        const int tn = (t < TSTEPS - 1) ? t + 1 : t;   // last: benign reload
        const int jqn = j0 + tn * 32 + quad * 8;
        // issue NEXT step's hT loads (consumed next iter -> full-step cover)
#pragma unroll
        for (int nt = 0; nt < 4; ++nt) {
            hb[nxt][nt]     = *(const s16x8*)(hT + (size_t)(nt * 16 + m) * N + jqn);
            hb[nxt][4 + nt] = *(const s16x8*)(hT + (size_t)(nt * 16 + m + 64) * N + jqn);
        }

        const unsigned long long mk = mrow[t >> 1];
        const unsigned mbyte = (unsigned)(mk >> ((t & 1) * 32 + quad * 8)) & 0xffu;

        const int bb = t * 32 + quad * 8;
        const int bidx = bb + (bb >> 3);
        float pv0[8], pv1[8];
#pragma unroll
        for (int jj = 0; jj < 8; ++jj) {
            float4 bd = BDl[bidx + jj];
            float w0 = fmaxf(A0 * bd.x, C0 * bd.y);
            float w1 = fmaxf(A1 * bd.z, C1 * bd.w);
            bool on = (mbyte >> jj) & 1u;
            pv0[jj] = on ? w0 : 0.0f;
            pv1[jj] = on ? w1 : 0.0f;
        }
        unsigned pu0[4], pu1[4];
#pragma unroll
        for (int q = 0; q < 4; ++q) {
            pu0[q] = pkbf(pv0[q * 2], pv0[q * 2 + 1]);
            pu1[q] = pkbf(pv1[q * 2], pv1[q * 2 + 1]);
        }
        s16x8 p0, p1;
        __builtin_memcpy(&p0, pu0, 16);
        __builtin_memcpy(&p1, pu1, 16);

#pragma unroll
        for (int nt = 0; nt < 4; ++nt) {
            acc[0][nt] = __builtin_amdgcn_mfma_f32_16x16x32_bf16(p0, hb[cur][nt], acc[0][nt], 0, 0, 0);
            acc[1][nt] = __builtin_amdgcn_mfma_f32_16x16x32_bf16(p1, hb[cur][4 + nt], acc[1][nt], 0, 0, 0);
        }
        accS[0] = __builtin_amdgcn_mfma_f32_16x16x32_bf16(p0, ones, accS[0], 0, 0, 0);
        accS[1] = __builtin_amdgcn_mfma_f32_16x16x32_bf16(p1, ones, accS[1], 0, 0, 0);
    }

    // ---- epilogue: transpose via LDS, coalesced atomic accumulate ----
    __syncthreads();   // BDl no longer needed; smem reused per-wave
    float* sm = smem + wave * 16 * 129;
#pragma unroll
    for (int h = 0; h < 2; ++h)
#pragma unroll
        for (int nt = 0; nt < 4; ++nt) {
            const int c = h * 64 + nt * 16 + m;
#pragma unroll
            for (int r = 0; r < 4; ++r)
                sm[(quad * 4 + r) * 129 + c] = acc[h][nt][r];
        }
    // wave-local: ds_write -> ds_read ordered by lgkmcnt (no barrier needed)
#pragma unroll
    for (int r16 = 0; r16 < 16; ++r16) {
        float v0 = sm[r16 * 129 + lane];
        float v1 = sm[r16 * 129 + 64 + lane];
        const size_t o = (size_t)(ibase + r16) * 128 + lane;
        atomicAdd(&Up[o], v0);
        atomicAdd(&Up[o + 64], v1);
    }
    if (m == 0) {
#pragma unroll
        for (int h = 0; h < 2; ++h)
#pragma unroll
            for (int r = 0; r < 4; ++r)
                atomicAdd(&Lp[h * N + ibase + quad * 4 + r], accS[h][r]);
    }
}

// ---------------------------------------------------------------------------
// Kernel 4: normalize: out = Up / Lp (4 MB read, 4 MB write).
// ---------------------------------------------------------------------------
__global__ __launch_bounds__(256) void k4_norm(const float* __restrict__ Up,
                                               const float* __restrict__ Lp,
                                               float* __restrict__ out) {
    const int base = (blockIdx.x * 256 + threadIdx.x) * 4;
    const int i = base >> 7, h = (base & 127) >> 6;
    float4 u = *(const float4*)(Up + base);
    float inv = 1.0f / Lp[h * N + i];
    float4 o; o.x = u.x * inv; o.y = u.y * inv; o.z = u.z * inv; o.w = u.w * inv;
    *(float4*)(out + base) = o;
}

extern "C" void kernel_launch(void* const* d_in, const int* in_sizes, int n_in,
                              void* d_out, int out_size, void* d_ws, size_t ws_size,
                              hipStream_t stream) {
    const float* x     = (const float*)d_in[0];
    const float* adj   = (const float*)d_in[1];
    const float* W     = (const float*)d_in[2];
    const float* a_src = (const float*)d_in[3];
    const float* a_dst = (const float*)d_in[4];
    float* out = (float*)d_out;
    char* ws = (char*)d_ws;

    size_t off = 0;
    unsigned short* hT = (unsigned short*)(ws + off); off += (size_t)128 * N * 2;
    float* As = (float*)(ws + off); off += (size_t)2 * N * 4;
    float* Cs = (float*)(ws + off); off += (size_t)2 * N * 4;
    float4* BD = (float4*)(ws + off); off += (size_t)N * 16;
    unsigned long long* bits = (unsigned long long*)(ws + off); off += (size_t)N * NW64 * 8;
    float* Up = (float*)(ws + off); off += (size_t)N * 128 * 4;
    float* Lp = (float*)(ws + off); off += (size_t)2 * N * 4;

    // zero the atomic accumulators (Up + Lp are contiguous)
    hipMemsetAsync(Up, 0, (size_t)N * 128 * 4 + (size_t)2 * N * 4, stream);

    k0_pack<<<N, 256, 0, stream>>>(adj, bits);
    k1_xw<<<N / 64, 256, 0, stream>>>(x, W, hT);
    k2_e<<<N / 256, 256, 0, stream>>>(hT, a_src, a_dst, As, Cs, BD);
    dim3 g3(N / 64, JC);
    k3_main<<<g3, 256, 0, stream>>>(bits, hT, As, Cs, BD, Up, Lp);
    k4_norm<<<(N * 128) / (256 * 4), 256, 0, stream>>>(Up, Lp, out);
}

// Round 9
// 435.333 us; speedup vs baseline: 1.2435x; 1.2435x over previous
//
#include <hip/hip_runtime.h>
#include <hip/hip_bf16.h>

#define N 8192
#define IND 128
#define OUTD 128
#define JC 8
#define JLEN 1024   /* N/JC */
#define SUBC 8      /* sub-chunks per block */
#define SUBJ 128    /* j per sub-chunk */
#define TSUB 4      /* 32-j steps per sub-chunk */
#define NW64 (N / 64)

typedef float f32x4 __attribute__((ext_vector_type(4)));
typedef short s16x8 __attribute__((ext_vector_type(8)));
typedef _Float16 f16;
typedef _Float16 f16x2 __attribute__((ext_vector_type(2)));
typedef _Float16 f16x4 __attribute__((ext_vector_type(4)));
typedef long long ll2 __attribute__((ext_vector_type(2)));
typedef unsigned int u32x4 __attribute__((ext_vector_type(4)));

static __device__ inline unsigned short f2bf(float f) {
    union { float f; unsigned u; } v; v.f = f;
    unsigned u = v.u + 0x7fffu + ((v.u >> 16) & 1u);
    return (unsigned short)(u >> 16);
}
static __device__ inline float bf2f(unsigned short b) {
    union { unsigned u; float f; } v; v.u = ((unsigned)b) << 16;
    return v.f;
}
static __device__ __forceinline__ unsigned pkbf(float a, float b) {
    __hip_bfloat162 t = __float22bfloat162_rn(make_float2(a, b));
    unsigned u;
    __builtin_memcpy(&u, &t, 4);
    return u;
}
// async 16B/lane global->LDS: dest = uniform base + lane*16
static __device__ __forceinline__ void async16(const void* g, void* l) {
    __builtin_amdgcn_global_load_lds(
        (const __attribute__((address_space(1))) unsigned int*)g,
        (__attribute__((address_space(3))) unsigned int*)l, 16, 0, 0);
}

// ---------------------------------------------------------------------------
// Kernel 0: compress binary adj (268 MB) -> bitmask (8.4 MB). Streaming read.
// ---------------------------------------------------------------------------
__global__ __launch_bounds__(256) void k0_pack(const float* __restrict__ adj,
                                               unsigned long long* __restrict__ bits) {
    const int row = blockIdx.x;
    const int wave = threadIdx.x >> 6, lane = threadIdx.x & 63;
    const float* src = adj + (size_t)row * N + wave * 2048;
    unsigned long long acc = 0;
#pragma unroll
    for (int t = 0; t < 32; ++t) {
        float v = src[t * 64 + lane];
        unsigned long long b = __ballot(v != 0.0f);
        if (lane == t) acc = b;
    }
    if (lane < 32)
        bits[(size_t)row * NW64 + wave * 32 + lane] = acc;
}

// ---------------------------------------------------------------------------
// Kernel 1: h = x @ W  (bf16 MFMA), store transposed bf16 hT[c][i] (128 x N).
// ---------------------------------------------------------------------------
__global__ __launch_bounds__(256) void k1_xw(const float* __restrict__ x,
                                             const float* __restrict__ W,
                                             unsigned short* __restrict__ hT) {
    __shared__ unsigned short Wl[128 * 130];
    const int tid = threadIdx.x;
    {
        int k = tid >> 1, n0 = (tid & 1) * 64;
        const float4* src = (const float4*)(W + k * 128 + n0);
#pragma unroll
        for (int v = 0; v < 16; ++v) {
            float4 f = src[v];
            int base = k * 130 + n0 + v * 4;
            Wl[base + 0] = f2bf(f.x);
            Wl[base + 1] = f2bf(f.y);
            Wl[base + 2] = f2bf(f.z);
            Wl[base + 3] = f2bf(f.w);
        }
    }
    __syncthreads();
    const int wave = tid >> 6, lane = tid & 63;
    const int m = lane & 15, quad = lane >> 4;
    const int ibase = blockIdx.x * 64 + wave * 16;
    const int irow = ibase + m;

    f32x4 acc[8];
#pragma unroll
    for (int t = 0; t < 8; ++t) acc[t] = (f32x4){0.f, 0.f, 0.f, 0.f};

#pragma unroll
    for (int ks = 0; ks < 4; ++ks) {
        const int k0 = ks * 32 + quad * 8;
        const float4* xp = (const float4*)(x + (size_t)irow * 128 + k0);
        float4 xa = xp[0], xb = xp[1];
        s16x8 afrag;
        afrag[0] = (short)f2bf(xa.x); afrag[1] = (short)f2bf(xa.y);
        afrag[2] = (short)f2bf(xa.z); afrag[3] = (short)f2bf(xa.w);
        afrag[4] = (short)f2bf(xb.x); afrag[5] = (short)f2bf(xb.y);
        afrag[6] = (short)f2bf(xb.z); afrag[7] = (short)f2bf(xb.w);
#pragma unroll
        for (int nt = 0; nt < 8; ++nt) {
            const int n = nt * 16 + m;
            s16x8 bfrag;
#pragma unroll
            for (int j = 0; j < 8; ++j)
                bfrag[j] = (short)Wl[(k0 + j) * 130 + n];
            acc[nt] = __builtin_amdgcn_mfma_f32_16x16x32_bf16(afrag, bfrag, acc[nt], 0, 0, 0);
        }
    }
#pragma unroll
    for (int nt = 0; nt < 8; ++nt) {
        const int c = nt * 16 + m;
        const int i0 = ibase + quad * 4;
        ushort4 pk;
        pk.x = f2bf(acc[nt][0]); pk.y = f2bf(acc[nt][1]);
        pk.z = f2bf(acc[nt][2]); pk.w = f2bf(acc[nt][3]);
        *(ushort4*)(hT + (size_t)c * N + i0) = pk;
    }
}

// ---------------------------------------------------------------------------
// Kernel 2: per-node separable arrays.
// w_ij = exp(leaky(es_i + ed_j)) = max(A_i*B_j, C_i*D_j)
// BDh[j] = uint2{ pack(B0,D0), pack(B1,D1) }  (bf16x2 each)
// ---------------------------------------------------------------------------
__global__ __launch_bounds__(256) void k2_e(const unsigned short* __restrict__ hT,
                                            const float* __restrict__ a_src,
                                            const float* __restrict__ a_dst,
                                            float* __restrict__ As, float* __restrict__ Cs,
                                            uint2* __restrict__ BDh) {
    const int i = blockIdx.x * 256 + threadIdx.x;
    float es0 = 0.f, ed0 = 0.f, es1 = 0.f, ed1 = 0.f;
#pragma unroll 8
    for (int c = 0; c < 128; ++c) {
        float v = bf2f(hT[(size_t)c * N + i]);
        float as = a_src[c], ad = a_dst[c];
        if (c < 64) { es0 += v * as; ed0 += v * ad; }
        else        { es1 += v * as; ed1 += v * ad; }
    }
    As[i]     = __expf(es0);
    As[N + i] = __expf(es1);
    Cs[i]     = __expf(0.2f * es0);
    Cs[N + i] = __expf(0.2f * es1);
    uint2 bd;
    bd.x = pkbf(__expf(ed0), __expf(0.2f * ed0));
    bd.y = pkbf(__expf(ed1), __expf(0.2f * ed1));
    BDh[i] = bd;
}

// ---------------------------------------------------------------------------
// Kernel 3 (main): ZERO global loads in the compute phase. Per 128-j
// sub-chunk, async-stage hT (32 KB, XOR granule swizzle -> conflict-free
// strided B-frag reads) + BDh (1 KB, bf16-packed) into LDS; masks via one
// 16B reg load. 4 steps of pure-LDS compute between barriers. Latency is
// paid once per sub-chunk and covered by 4 co-resident blocks.
// grid = (128 i-tiles, 8 j-chunks); block = 256 thr = 4 waves, 16 rows/wave.
// ---------------------------------------------------------------------------
__global__ __launch_bounds__(256, 4) void k3_main(const unsigned long long* __restrict__ bits,
                                                  const unsigned short* __restrict__ hTg,
                                                  const float* __restrict__ As,
                                                  const float* __restrict__ Cs,
                                                  const uint2* __restrict__ BDh,
                                                  f16* __restrict__ Up,
                                                  float* __restrict__ Lp) {
    __shared__ float4 smem4[2112];                       // 33792 B
    unsigned short* hTl = (unsigned short*)smem4;        // 32 KB
    uint2* bdl = (uint2*)((char*)smem4 + 32768);         // 1 KB
    const int tid = threadIdx.x;
    const int wave = tid >> 6, lane = tid & 63;
    const int m = lane & 15, quad = lane >> 4;
    const int ibase = blockIdx.x * 64 + wave * 16;
    const int irow = ibase + m;
    const int jc = blockIdx.y;
    const int j0 = jc * JLEN;

    const float A0 = As[irow], C0 = Cs[irow];
    const float A1 = As[N + irow], C1 = Cs[N + irow];

    f32x4 acc[2][4];
#pragma unroll
    for (int h = 0; h < 2; ++h)
#pragma unroll
        for (int nt = 0; nt < 4; ++nt) acc[h][nt] = (f32x4){0.f, 0.f, 0.f, 0.f};
    f32x4 accS[2];
    accS[0] = (f32x4){0.f, 0.f, 0.f, 0.f};
    accS[1] = (f32x4){0.f, 0.f, 0.f, 0.f};

    s16x8 ones;
#pragma unroll
    for (int t = 0; t < 8; ++t) ones[t] = (short)0x3F80;

    const int crow = lane >> 4;   // row-in-group for staging
    const int gd = lane & 15;     // dest granule for staging

#pragma unroll 1
    for (int sc = 0; sc < SUBC; ++sc) {
        const int jb = j0 + sc * SUBJ;
        if (sc) __syncthreads();               // prev sub-chunk reads done
        // masks: 2 uint64 = this lane's row, 128 j
        ll2 mk = *(const ll2*)(bits + (size_t)irow * NW64 + (jb >> 6));
        // stage BD (1 KB, wave 0)
        if (wave == 0)
            async16(BDh + jb + lane * 2, bdl);
        // stage hT: 8 async16/wave, 4 rows each, XOR-swizzled source granule
#pragma unroll
        for (int rr = 0; rr < 8; ++rr) {
            const int rg = wave * 8 + rr;      // row group 0..31
            const int c = rg * 4 + crow;       // 0..127
            const int gs = gd ^ (c & 7);
            async16(hTg + (size_t)c * N + jb + gs * 8, hTl + rg * 512);
        }
        __syncthreads();                       // staging visible

#pragma unroll
        for (int t = 0; t < TSUB; ++t) {
            // BD: 8 j (16 packed bf16 pairs) -> 4 x b128
            u32x4 bq[4];
            const u32x4* bp = (const u32x4*)(bdl + (t * 32 + quad * 8));
#pragma unroll
            for (int z = 0; z < 4; ++z) bq[z] = bp[z];
            // hT fragments from LDS (swizzled granule)
            s16x8 h0[4], h1[4];
            const int gr = t * 4 + quad;
#pragma unroll
            for (int nt = 0; nt < 4; ++nt) {
                const int c0 = nt * 16 + m;
                const int go = (gr ^ (c0 & 7)) * 8;
                h0[nt] = *(const s16x8*)(hTl + c0 * 128 + go);
                h1[nt] = *(const s16x8*)(hTl + (c0 + 64) * 128 + go);
            }
            const unsigned long long mw =
                (t < 2) ? (unsigned long long)mk[0] : (unsigned long long)mk[1];
            const unsigned mbyte = (unsigned)(mw >> ((t & 1) * 32 + quad * 8)) & 0xffu;

            float pv0[8], pv1[8];
#pragma unroll
            for (int jj = 0; jj < 8; ++jj) {
                const unsigned p0u = bq[jj >> 1][(jj & 1) * 2];
                const unsigned p1u = bq[jj >> 1][(jj & 1) * 2 + 1];
                float B0 = __uint_as_float(p0u << 16);
                float D0 = __uint_as_float(p0u & 0xffff0000u);
                float B1 = __uint_as_float(p1u << 16);
                float D1 = __uint_as_float(p1u & 0xffff0000u);
                float w0 = fmaxf(A0 * B0, C0 * D0);
                float w1 = fmaxf(A1 * B1, C1 * D1);
                bool on = (mbyte >> jj) & 1u;
                pv0[jj] = on ? w0 : 0.0f;
                pv1[jj] = on ? w1 : 0.0f;
            }
            unsigned pu0[4], pu1[4];
#pragma unroll
            for (int q = 0; q < 4; ++q) {
                pu0[q] = pkbf(pv0[q * 2], pv0[q * 2 + 1]);
                pu1[q] = pkbf(pv1[q * 2], pv1[q * 2 + 1]);
            }
            s16x8 p0, p1;
            __builtin_memcpy(&p0, pu0, 16);
            __builtin_memcpy(&p1, pu1, 16);

#pragma unroll
            for (int nt = 0; nt < 4; ++nt) {
                acc[0][nt] = __builtin_amdgcn_mfma_f32_16x16x32_bf16(p0, h0[nt], acc[0][nt], 0, 0, 0);
                acc[1][nt] = __builtin_amdgcn_mfma_f32_16x16x32_bf16(p1, h1[nt], acc[1][nt], 0, 0, 0);
            }
            accS[0] = __builtin_amdgcn_mfma_f32_16x16x32_bf16(p0, ones, accS[0], 0, 0, 0);
            accS[1] = __builtin_amdgcn_mfma_f32_16x16x32_bf16(p1, ones, accS[1], 0, 0, 0);
        }
    }

    // ---- epilogue: transpose via LDS (wave-local), coalesced fp16 stores ----
    __syncthreads();
    float* smf = (float*)smem4 + wave * (16 * 129);
#pragma unroll
    for (int h = 0; h < 2; ++h)
#pragma unroll
        for (int nt = 0; nt < 4; ++nt) {
            const int c = h * 64 + nt * 16 + m;
#pragma unroll
            for (int r = 0; r < 4; ++r)
                smf[(quad * 4 + r) * 129 + c] = acc[h][nt][r];
        }
    // same-wave ds_write -> ds_read: DS pipe is in-order per wave
    f16* Ub = Up + (size_t)jc * N * 128;
#pragma unroll
    for (int r16 = 0; r16 < 16; ++r16) {
        float v0 = smf[r16 * 129 + lane * 2];
        float v1 = smf[r16 * 129 + lane * 2 + 1];
        f16x2 pk; pk[0] = (f16)v0; pk[1] = (f16)v1;
        *(f16x2*)(Ub + (size_t)(ibase + r16) * 128 + lane * 2) = pk;
    }
    if (m == 0) {
#pragma unroll
        for (int h = 0; h < 2; ++h)
#pragma unroll
            for (int r = 0; r < 4; ++r)
                Lp[((size_t)jc * 2 + h) * N + ibase + quad * 4 + r] = accS[h][r];
    }
}

// ---------------------------------------------------------------------------
// Kernel 4: sum fp16 partials over j-chunks, divide by row-sum.
// ---------------------------------------------------------------------------
__global__ __launch_bounds__(256) void k4_reduce(const f16* __restrict__ Up,
                                                 const float* __restrict__ Lp,
                                                 float* __restrict__ out) {
    const int base = (blockIdx.x * 256 + threadIdx.x) * 4;
    const int i = base >> 7, c = base & 127, h = c >> 6;
    float su0 = 0.f, su1 = 0.f, su2 = 0.f, su3 = 0.f, sl = 0.f;
#pragma unroll
    for (int jcc = 0; jcc < JC; ++jcc) {
        f16x4 u = *(const f16x4*)(Up + (size_t)jcc * N * 128 + base);
        su0 += (float)u[0]; su1 += (float)u[1];
        su2 += (float)u[2]; su3 += (float)u[3];
        sl += Lp[((size_t)jcc * 2 + h) * N + i];
    }
    float inv = 1.0f / sl;
    float4 o; o.x = su0 * inv; o.y = su1 * inv; o.z = su2 * inv; o.w = su3 * inv;
    *(float4*)(out + base) = o;
}

extern "C" void kernel_launch(void* const* d_in, const int* in_sizes, int n_in,
                              void* d_out, int out_size, void* d_ws, size_t ws_size,
                              hipStream_t stream) {
    const float* x     = (const float*)d_in[0];
    const float* adj   = (const float*)d_in[1];
    const float* W     = (const float*)d_in[2];
    const float* a_src = (const float*)d_in[3];
    const float* a_dst = (const float*)d_in[4];
    float* out = (float*)d_out;
    char* ws = (char*)d_ws;

    size_t off = 0;
    unsigned short* hT = (unsigned short*)(ws + off); off += (size_t)128 * N * 2;
    float* As = (float*)(ws + off); off += (size_t)2 * N * 4;
    float* Cs = (float*)(ws + off); off += (size_t)2 * N * 4;
    uint2* BDh = (uint2*)(ws + off); off += (size_t)N * 8;
    unsigned long long* bits = (unsigned long long*)(ws + off); off += (size_t)N * NW64 * 8;
    f16* Up = (f16*)(ws + off); off += (size_t)JC * N * 128 * 2;
    float* Lp = (float*)(ws + off); off += (size_t)JC * 2 * N * 4;

    k0_pack<<<N, 256, 0, stream>>>(adj, bits);
    k1_xw<<<N / 64, 256, 0, stream>>>(x, W, hT);
    k2_e<<<N / 256, 256, 0, stream>>>(hT, a_src, a_dst, As, Cs, BDh);
    dim3 g3(N / 64, JC);
    k3_main<<<g3, 256, 0, stream>>>(bits, hT, As, Cs, BDh, Up, Lp);
    k4_reduce<<<(N * 128) / (256 * 4), 256, 0, stream>>>(Up, Lp, out);
}